// Round 11
// baseline (1404.516 us; speedup 1.0000x reference)
//
#include <hip/hip_runtime.h>
#include <math.h>

// Problem constants: B=8, N=M=2048, D=3.
#define BB 8
#define NN 2048
#define L2E 1.4426950408889634f
#define LN2 0.6931471805599453f
#define PI_F 3.14159265358979f
#define CLIP 0.999999f

constexpr int TB   = 128;
constexpr int T16  = NN / TB;              // 16
constexpr int NXX  = T16 * (T16 + 1) / 2;  // 136
constexpr int NT   = 2 * NXX + T16 * T16;  // 528 tiles per batch
constexpr int SARR = BB * NN;              // 16384

// tile index -> (kind, I, J). kind 0: xx (I<=J), 1: yy (I<=J), 2: xy (all)
__device__ __forceinline__ void decode_tile(int bx, int& kind, int& I, int& J) {
    if (bx < NXX) kind = 0;
    else if (bx < 2 * NXX) { kind = 1; bx -= NXX; }
    else { kind = 2; bx -= 2 * NXX; }
    if (kind < 2) {
        int idx = bx; I = 0;
        for (;;) { int len = T16 - I; if (idx < len) { J = I + idx; break; } idx -= len; I++; }
    } else { I = bx >> 4; J = bx & 15; }
}

// raw acos via A&S 4.4.45 (|err| <= 7e-5 rad), input pre-clipped
__device__ __forceinline__ float acos_raw(float d) {
    const float u = fabsf(d);
    float pl = fmaf(u, -0.0187293f, 0.0742610f);
    pl = fmaf(u, pl, -0.2121144f); pl = fmaf(u, pl, 1.5707288f);
    const float rt = __builtin_amdgcn_sqrtf(1.f - u) * pl;
    return (d >= 0.f) ? rt : (PI_F - rt);
}

// 16-slot (M,S) partial merge with zero-mass-slot guard -> negepl2*(M+log2 S)
__device__ __forceinline__ float finish16(const float2* __restrict__ P, size_t gi,
                                          float negepl2) {
    float M = -INFINITY, S = 0.f;
#pragma unroll
    for (int u = 0; u < T16; u++) {
        const float2 pr = P[(size_t)u * SARR + gi];
        if (pr.y > 0.f) {
            const float nm = fmaxf(M, pr.x);
            S = S * __builtin_amdgcn_exp2f(M - nm) + pr.y * __builtin_amdgcn_exp2f(pr.x - nm);
            M = nm;
        }
    }
    S = fmaxf(S, 1e-38f);
    return negepl2 * (M + __builtin_amdgcn_logf(S));
}

// ---------------------------------------------------------------------------
// pack: gxw/gyw = log_weights * log2(e)
// ---------------------------------------------------------------------------
__global__ __launch_bounds__(256)
void pack_kernel(const float* __restrict__ alpha, const float* __restrict__ beta,
                 float* __restrict__ gxw, float* __restrict__ gyw)
{
    const int gid = blockIdx.x * 256 + threadIdx.x;
    const int o = gid >> 14, i = gid & (SARR - 1);
    const float v = (o == 0) ? alpha[i] : beta[i];
    const float g = ((v > 0.f) ? logf(fmaxf(v, 1e-30f)) : -1e5f) * L2E;
    if (o == 0) gxw[i] = g; else gyw[i] = g;
}

// ---------------------------------------------------------------------------
// One-time geometry pass over FULL tile grids (kind = blockIdx.z).
// Stores THETA of the per-row / per-col max-dot (eps-independent).
// ---------------------------------------------------------------------------
__global__ __launch_bounds__(256)
void maxes_kernel(const float* __restrict__ x, const float* __restrict__ y,
                  float* __restrict__ Rxx, float* __restrict__ Ryy,
                  float* __restrict__ Rxy, float* __restrict__ Cxy)
{
    __shared__ float4 p1s[TB], p2s[TB];
    __shared__ float colred[4][TB];
    const int I = blockIdx.x >> 4, J = blockIdx.x & 15;
    const int b = blockIdx.y, kind = blockIdx.z, t = threadIdx.x;
    const float* P1 = (kind == 1) ? y : x;
    const float* P2 = (kind == 0) ? x : y;
    if (t < TB) {
        size_t gi = (size_t)b * NN + (size_t)I * TB + t;
        p1s[t] = make_float4(P1[gi * 3], P1[gi * 3 + 1], P1[gi * 3 + 2], 0.f);
    } else {
        int u = t - TB; size_t gi = (size_t)b * NN + (size_t)J * TB + u;
        p2s[u] = make_float4(P2[gi * 3], P2[gi * 3 + 1], P2[gi * 3 + 2], 0.f);
    }
    __syncthreads();
    const int lane = t & 63, wv = t >> 6, colg = lane & 7, rowg = lane >> 3;
    const int r0 = wv * 32 + rowg * 4;
    float4 pr[4];
#pragma unroll
    for (int rr = 0; rr < 4; rr++) pr[rr] = p1s[r0 + rr];
    float rmx[4] = {-2.f, -2.f, -2.f, -2.f};
    float cmx[16];
#pragma unroll
    for (int j = 0; j < 16; j++) cmx[j] = -2.f;
#pragma unroll
    for (int j = 0; j < 16; j++) {
        const float4 q = p2s[colg + 8 * j];
#pragma unroll
        for (int rr = 0; rr < 4; rr++) {
            float d = fmaf(pr[rr].x, q.x, fmaf(pr[rr].y, q.y, pr[rr].z * q.z));
            rmx[rr] = fmaxf(rmx[rr], d);
            cmx[j] = fmaxf(cmx[j], d);
        }
    }
#pragma unroll
    for (int rr = 0; rr < 4; rr++) {
        float v = rmx[rr];
        v = fmaxf(v, __shfl_xor(v, 1)); v = fmaxf(v, __shfl_xor(v, 2));
        v = fmaxf(v, __shfl_xor(v, 4));
        rmx[rr] = v;
    }
    if (colg == 0) {
        float* R = (kind == 0) ? Rxx : (kind == 1) ? Ryy : Rxy;
        const size_t base = ((size_t)b * T16 + J) * NN + (size_t)I * TB + r0;
#pragma unroll
        for (int rr = 0; rr < 4; rr++)
            R[base + rr] = acos_raw(fminf(fmaxf(rmx[rr], -CLIP), CLIP));
    }
    if (kind == 2) {
#pragma unroll
        for (int j = 0; j < 16; j++) {
            float v = cmx[j];
            v = fmaxf(v, __shfl_xor(v, 8)); v = fmaxf(v, __shfl_xor(v, 16));
            v = fmaxf(v, __shfl_xor(v, 32));
            cmx[j] = v;
        }
        if (rowg == 0) {
#pragma unroll
            for (int j = 0; j < 16; j++) colred[wv][colg + 8 * j] = cmx[j];
        }
        __syncthreads();
        if (t < TB) {
            const float v = fmaxf(fmaxf(colred[0][t], colred[1][t]),
                                  fmaxf(colred[2][t], colred[3][t]));
            Cxy[((size_t)b * T16 + I) * NN + (size_t)J * TB + t] =
                acos_raw(fminf(fmaxf(v, -CLIP), CLIP));
        }
    }
}

// ---------------------------------------------------------------------------
// Fused tile kernel. Staging per thread (0-127: row strip, 128-255: col strip):
//   mode 0: h = g (init weights). mode 1/2: merge 16 slots of the previous
//   step's partials -> r (mode 2: 0.5-avg with Aold), write Anew (benign
//   identical-value race), h = g + r*ieL2E. LDS max-reduce h per strip -> G,
//   W = 2^{h-G}. Then the R6 scalar pair loop; partials written transposed.
// Side s: {0:ax/gxw/pAX, 1:by/gyw/pBY, 2:ay/gyw/pAY, 3:bx/gxw/pBX}
// ---------------------------------------------------------------------------
struct TileArgs {
    const float* x; const float* y;
    const float* gxw; const float* gyw;
    const float* Rxx; const float* Ryy; const float* Rxy; const float* Cxy;
    const float2* pOld[4]; float2* pNew[4];
    const float* Aold[4];  float* Anew[4];
};

__global__ __launch_bounds__(256)
void tile_kernel(TileArgs A, float ieh, float pi_ieh,
                 float negepl2, float ieL2E, int mode)
{
    __shared__ float4 p1s[TB], p2s[TB];   // {px,py,pz,W}
    __shared__ float srs[TB], scs[TB];    // per-row / per-col shifts (scaled)
    __shared__ float sh[256];
    __shared__ float colpart[4][TB];
    int kind, I, J; decode_tile(blockIdx.x, kind, I, J);
    const int b = blockIdx.y, t = threadIdx.x;
    const float* P1 = (kind == 1) ? A.y : A.x;
    const float* P2 = (kind == 0) ? A.x : A.y;
    const int o1 = (kind == 0) ? 0 : (kind == 1) ? 1 : 3;   // row-strip side
    const int o2 = (kind == 0) ? 0 : (kind == 1) ? 1 : 2;   // col-strip side
    float2* rowOut = A.pNew[o2 == 2 ? 3 : o1];              // kind2 row out = pBX(3)
    float2* colOut = A.pNew[o2];
    const bool diag = (kind < 2) && (I == J);
    const float* Rrow = (kind == 0) ? A.Rxx : (kind == 1) ? A.Ryy : A.Rxy;
    const float* Csrc = (kind == 0) ? A.Rxx : (kind == 1) ? A.Ryy : A.Cxy;

    // ---- fused combine + weight staging ----
    const int half = t >> 7, loc = t & 127;
    const int side  = half ? o2 : o1;
    const int strip = half ? J : I;
    const size_t gi = (size_t)b * NN + (size_t)strip * TB + loc;
    const float g = (side == 0 || side == 3) ? A.gxw[gi] : A.gyw[gi];
    float h = g;
    if (mode != 0) {
        float r = finish16(A.pOld[side], gi, negepl2);
        if (mode == 2) r = 0.5f * (r + A.Aold[side][gi]);
        A.Anew[side][gi] = r;             // identical across writers — benign
        h = fmaf(r, ieL2E, g);
    }
    sh[t] = h;
    __syncthreads();
    const int base = t & 128;
    for (int st = 64; st; st >>= 1) {
        if (loc < st) sh[base + loc] = fmaxf(sh[base + loc], sh[base + loc + st]);
        __syncthreads();
    }
    const float G1 = sh[0], G2 = sh[128];
    const float W = __builtin_amdgcn_exp2f(h - (half ? G2 : G1));

    if (t < TB) {
        p1s[t] = make_float4(P1[gi * 3], P1[gi * 3 + 1], P1[gi * 3 + 2], W);
        srs[t] = Rrow[((size_t)b * T16 + J) * NN + (size_t)I * TB + t] * ieh;
    } else {
        p2s[loc] = make_float4(P2[gi * 3], P2[gi * 3 + 1], P2[gi * 3 + 2], W);
        scs[loc] = Csrc[((size_t)b * T16 + I) * NN + (size_t)J * TB + loc] * ieh;
    }
    __syncthreads();

    // ---- pair loop (scalar, R6 structure) ----
    const int lane = t & 63, wv = t >> 6, colg = lane & 7, rowg = lane >> 3;
    const int r0 = wv * 32 + rowg * 4;
    float4 pr[4]; float srr[4];
#pragma unroll
    for (int rr = 0; rr < 4; rr++) { pr[rr] = p1s[r0 + rr]; srr[rr] = srs[r0 + rr]; }
    float racc[4] = {0.f, 0.f, 0.f, 0.f};
    float cacc[16];
#pragma unroll
    for (int j = 0; j < 16; j++) cacc[j] = 0.f;

    // acos poly coefficients pre-scaled by ieh (log2 domain)
    const float K0 = 1.5707288f * ieh, K1 = -0.2121144f * ieh;
    const float K2 = 0.0742610f * ieh, K3 = -0.0187293f * ieh;

#pragma unroll
    for (int j = 0; j < 16; j++) {
        const float4 q = p2s[colg + 8 * j];
        const float sc = scs[colg + 8 * j];
#pragma unroll
        for (int rr = 0; rr < 4; rr++) {
            const float4 p = pr[rr];
            const float d = fmaf(p.x, q.x, fmaf(p.y, q.y, p.z * q.z));
            const float u = fminf(fabsf(d), CLIP);
            float pl = fmaf(u, K3, K2); pl = fmaf(u, pl, K1); pl = fmaf(u, pl, K0);
            const float rt = __builtin_amdgcn_sqrtf(1.f - u) * pl;
            const float ach = (d >= 0.f) ? rt : (pi_ieh - rt);
            racc[rr] = fmaf(q.w, __builtin_amdgcn_exp2f(srr[rr] - ach), racc[rr]);
            cacc[j]  = fmaf(p.w, __builtin_amdgcn_exp2f(sc - ach), cacc[j]);
        }
    }

    // col sums: reduce across rowg (lane bits 3..5)
#pragma unroll
    for (int j = 0; j < 16; j++) {
        float v = cacc[j];
        v += __shfl_xor(v, 8); v += __shfl_xor(v, 16); v += __shfl_xor(v, 32);
        cacc[j] = v;
    }
    if (rowg == 0) {
#pragma unroll
        for (int j = 0; j < 16; j++) colpart[wv][colg + 8 * j] = cacc[j];
    }
    // row sums: reduce across colg (lane bits 0..2)
#pragma unroll
    for (int rr = 0; rr < 4; rr++) {
        float v = racc[rr];
        v += __shfl_xor(v, 1); v += __shfl_xor(v, 2); v += __shfl_xor(v, 4);
        racc[rr] = v;
    }
    if (colg == 0) {
        const size_t gr = (size_t)J * SARR + (size_t)b * NN + (size_t)I * TB + r0;
#pragma unroll
        for (int rr = 0; rr < 4; rr++)
            rowOut[gr + rr] = make_float2(G2 - srr[rr], racc[rr]);
    }
    __syncthreads();
    if (!diag && t < TB) {
        const float v = colpart[0][t] + colpart[1][t] + colpart[2][t] + colpart[3][t];
        const size_t gc = (size_t)I * SARR + (size_t)b * NN + (size_t)J * TB + t;
        colOut[gc] = make_float2(G1 - scs[t], v);
    }
}

// ---------------------------------------------------------------------------
// final: finish all 4 potential sides from the last partials and reduce.
// out[b] = sum_n alpha*(bx-ax) + sum_m beta*(ay-by)
// ---------------------------------------------------------------------------
__global__ __launch_bounds__(256)
void final_kernel(const float2* __restrict__ pAX, const float2* __restrict__ pBY,
                  const float2* __restrict__ pAY, const float2* __restrict__ pBX,
                  const float* __restrict__ alpha, const float* __restrict__ beta,
                  float* __restrict__ out, float negepl2)
{
    const int b = blockIdx.x, t = threadIdx.x;
    float acc = 0.f;
    for (int n = t; n < NN; n += 256) {
        const size_t gi = (size_t)b * NN + n;
        const float axv = finish16(pAX, gi, negepl2);
        const float bxv = finish16(pBX, gi, negepl2);
        const float ayv = finish16(pAY, gi, negepl2);
        const float byv = finish16(pBY, gi, negepl2);
        acc += alpha[gi] * (bxv - axv) + beta[gi] * (ayv - byv);
    }
    __shared__ float red[256];
    red[t] = acc;
    __syncthreads();
    for (int st = 128; st > 0; st >>= 1) {
        if (t < st) red[t] += red[t + st];
        __syncthreads();
    }
    if (t == 0) out[b] = red[0];
}

// ---------------------------------------------------------------------------
extern "C" void kernel_launch(void* const* d_in, const int* in_sizes, int n_in,
                              void* d_out, int out_size, void* d_ws, size_t ws_size,
                              hipStream_t stream)
{
    const float* alpha = (const float*)d_in[0];
    const float* x     = (const float*)d_in[1];
    const float* beta  = (const float*)d_in[2];
    const float* y     = (const float*)d_in[3];
    float* out = (float*)d_out;
    float* ws  = (float*)d_ws;

    const size_t S = SARR;
    float* gxw = ws;
    float* gyw = ws + S;
    float* Rxx = ws + 2 * S;               // 16*S each (theta of max-dot)
    float* Ryy = Rxx + 16 * S;
    float* Rxy = Ryy + 16 * S;
    float* Cxy = Rxy + 16 * S;
    float* Ab  = Cxy + 16 * S;             // A buffers: 2 x 4 x S
    float* Pb  = Ab + 8 * S;               // partials: 2 x 4 x 32*S floats
    const size_t PSZ = (size_t)S * T16;    // float2 per side
    float2* Pbuf[2][4];
    float*  Abuf[2][4];
    for (int pb = 0; pb < 2; pb++)
        for (int s2 = 0; s2 < 4; s2++) {
            Pbuf[pb][s2] = (float2*)Pb + ((size_t)pb * 4 + s2) * PSZ;
            Abuf[pb][s2] = Ab + ((size_t)pb * 4 + s2) * S;
        }

    const float EPS[8] = {4.0f, 4.0f, 1.0f, 0.25f, 0.0625f, 0.015625f, 0.00390625f, 0.0025f};

    pack_kernel<<<(2 * SARR) / 256, 256, 0, stream>>>(alpha, beta, gxw, gyw);
    maxes_kernel<<<dim3(256, BB, 3), 256, 0, stream>>>(x, y, Rxx, Ryy, Rxy, Cxy);

    TileArgs TA;
    TA.x = x; TA.y = y; TA.gxw = gxw; TA.gyw = gyw;
    TA.Rxx = Rxx; TA.Ryy = Ryy; TA.Rxy = Rxy; TA.Cxy = Cxy;

    for (int j = 0; j < 10; j++) {
        const int mode = (j == 0) ? 0 : (j == 1) ? 1 : 2;
        const float mainEps = EPS[(j == 0) ? 0 : ((j - 1 < 7) ? j - 1 : 7)];
        const float prevEps = EPS[(j <= 2) ? 0 : ((j - 2 < 7) ? j - 2 : 7)];
        const float ieh = 0.5f * (1.f / mainEps) * L2E;
        for (int s2 = 0; s2 < 4; s2++) {
            TA.pOld[s2] = Pbuf[(j + 1) & 1][s2];   // previous step's partials
            TA.pNew[s2] = Pbuf[j & 1][s2];
            TA.Aold[s2] = Abuf[(j + 1) & 1][s2];
            TA.Anew[s2] = Abuf[j & 1][s2];
        }
        tile_kernel<<<dim3(NT, BB), 256, 0, stream>>>(
            TA, ieh, PI_F * ieh, -(prevEps * LN2), (1.f / mainEps) * L2E, mode);
    }

    // last tile dispatch (j=9) wrote Pbuf[1]
    final_kernel<<<BB, 256, 0, stream>>>(
        Pbuf[1][0], Pbuf[1][1], Pbuf[1][2], Pbuf[1][3],
        alpha, beta, out, -(EPS[7] * LN2));
}

// Round 12
// 690.322 us; speedup vs baseline: 2.0346x; 2.0346x over previous
//
#include <hip/hip_runtime.h>
#include <math.h>

// Problem constants: B=8, N=M=2048, D=3.
#define BB 8
#define NN 2048
#define L2E 1.4426950408889634f
#define LN2 0.6931471805599453f
#define PI_F 3.14159265358979f
#define CLIP 0.999999f

constexpr int TB   = 128;
constexpr int T16  = NN / TB;              // 16
constexpr int NXX  = T16 * (T16 + 1) / 2;  // 136
constexpr int NT   = 2 * NXX + T16 * T16;  // 528 tiles per batch
constexpr int SARR = BB * NN;              // 16384

// tile index -> (kind, I, J). kind 0: xx (I<=J), 1: yy (I<=J), 2: xy (all)
__device__ __forceinline__ void decode_tile(int bx, int& kind, int& I, int& J) {
    if (bx < NXX) kind = 0;
    else if (bx < 2 * NXX) { kind = 1; bx -= NXX; }
    else { kind = 2; bx -= 2 * NXX; }
    if (kind < 2) {
        int idx = bx; I = 0;
        for (;;) { int len = T16 - I; if (idx < len) { J = I + idx; break; } idx -= len; I++; }
    } else { I = bx >> 4; J = bx & 15; }
}

// raw acos via A&S 4.4.45 (|err| <= 7e-5 rad), input pre-clipped
__device__ __forceinline__ float acos_raw(float d) {
    const float u = fabsf(d);
    float pl = fmaf(u, -0.0187293f, 0.0742610f);
    pl = fmaf(u, pl, -0.2121144f); pl = fmaf(u, pl, 1.5707288f);
    const float rt = __builtin_amdgcn_sqrtf(1.f - u) * pl;
    return (d >= 0.f) ? rt : (PI_F - rt);
}

// 16-slot (M,S) partial merge with zero-mass-slot guard -> negepl2*(M+log2 S)
__device__ __forceinline__ float finish16(const float2* __restrict__ P, size_t gi,
                                          float negepl2) {
    float M = -INFINITY, S = 0.f;
#pragma unroll
    for (int u = 0; u < T16; u++) {
        const float2 pr = P[(size_t)u * SARR + gi];
        if (pr.y > 0.f) {
            const float nm = fmaxf(M, pr.x);
            S = S * __builtin_amdgcn_exp2f(M - nm) + pr.y * __builtin_amdgcn_exp2f(pr.x - nm);
            M = nm;
        }
    }
    S = fmaxf(S, 1e-38f);
    return negepl2 * (M + __builtin_amdgcn_logf(S));
}

// ---------------------------------------------------------------------------
// pack: initial g = log_weights * log2(e); emit W = 2^{g-G}, per-128-block G.
// o in {0:a_x(x),1:b_y(y),2:a_y-side(y),3:b_x-side(x)}
// ---------------------------------------------------------------------------
__global__ __launch_bounds__(256)
void pack_kernel(const float* __restrict__ alpha, const float* __restrict__ beta,
                 float* __restrict__ gxw, float* __restrict__ gyw,
                 float* __restrict__ Wall, float* __restrict__ Gall)
{
    const int tid = threadIdx.x;
    const int gid = blockIdx.x * 256 + tid;
    const int o = gid >> 14, i = gid & (SARR - 1);
    const float* w = (o == 0 || o == 3) ? alpha : beta;
    const float v = w[i];
    const float g = ((v > 0.f) ? logf(fmaxf(v, 1e-30f)) : -1e5f) * L2E;
    if (o == 0) gxw[i] = g;
    if (o == 1) gyw[i] = g;
    __shared__ float red[256];
    red[tid] = g;
    __syncthreads();
    const int base = tid & 128, loc = tid & 127;
    for (int st = 64; st; st >>= 1) {
        if (loc < st) red[base + loc] = fmaxf(red[base + loc], red[base + loc + st]);
        __syncthreads();
    }
    const float G = red[base];
    Wall[gid] = __builtin_amdgcn_exp2f(g - G);
    if (loc == 0) Gall[gid >> 7] = G;
}

// ---------------------------------------------------------------------------
// One-time geometry pass over FULL tile grids (kind = blockIdx.z).
// Stores THETA of the per-row / per-col max-dot (eps-independent).
// Also zeroes out[] (final kernel accumulates with atomics).
// ---------------------------------------------------------------------------
__global__ __launch_bounds__(256)
void maxes_kernel(const float* __restrict__ x, const float* __restrict__ y,
                  float* __restrict__ Rxx, float* __restrict__ Ryy,
                  float* __restrict__ Rxy, float* __restrict__ Cxy,
                  float* __restrict__ out)
{
    __shared__ float4 p1s[TB], p2s[TB];
    __shared__ float colred[4][TB];
    const int I = blockIdx.x >> 4, J = blockIdx.x & 15;
    const int b = blockIdx.y, kind = blockIdx.z, t = threadIdx.x;
    if (blockIdx.x == 0 && b == 0 && kind == 0 && t < BB) out[t] = 0.f;
    const float* P1 = (kind == 1) ? y : x;
    const float* P2 = (kind == 0) ? x : y;
    if (t < TB) {
        size_t gi = (size_t)b * NN + (size_t)I * TB + t;
        p1s[t] = make_float4(P1[gi * 3], P1[gi * 3 + 1], P1[gi * 3 + 2], 0.f);
    } else {
        int u = t - TB; size_t gi = (size_t)b * NN + (size_t)J * TB + u;
        p2s[u] = make_float4(P2[gi * 3], P2[gi * 3 + 1], P2[gi * 3 + 2], 0.f);
    }
    __syncthreads();
    const int lane = t & 63, wv = t >> 6, colg = lane & 7, rowg = lane >> 3;
    const int r0 = wv * 32 + rowg * 4;
    float4 pr[4];
#pragma unroll
    for (int rr = 0; rr < 4; rr++) pr[rr] = p1s[r0 + rr];
    float rmx[4] = {-2.f, -2.f, -2.f, -2.f};
    float cmx[16];
#pragma unroll
    for (int j = 0; j < 16; j++) cmx[j] = -2.f;
#pragma unroll
    for (int j = 0; j < 16; j++) {
        const float4 q = p2s[colg + 8 * j];
#pragma unroll
        for (int rr = 0; rr < 4; rr++) {
            float d = fmaf(pr[rr].x, q.x, fmaf(pr[rr].y, q.y, pr[rr].z * q.z));
            rmx[rr] = fmaxf(rmx[rr], d);
            cmx[j] = fmaxf(cmx[j], d);
        }
    }
#pragma unroll
    for (int rr = 0; rr < 4; rr++) {
        float v = rmx[rr];
        v = fmaxf(v, __shfl_xor(v, 1)); v = fmaxf(v, __shfl_xor(v, 2));
        v = fmaxf(v, __shfl_xor(v, 4));
        rmx[rr] = v;
    }
    if (colg == 0) {
        float* R = (kind == 0) ? Rxx : (kind == 1) ? Ryy : Rxy;
        const size_t base = ((size_t)b * T16 + J) * NN + (size_t)I * TB + r0;
#pragma unroll
        for (int rr = 0; rr < 4; rr++)
            R[base + rr] = acos_raw(fminf(fmaxf(rmx[rr], -CLIP), CLIP));
    }
    if (kind == 2) {
#pragma unroll
        for (int j = 0; j < 16; j++) {
            float v = cmx[j];
            v = fmaxf(v, __shfl_xor(v, 8)); v = fmaxf(v, __shfl_xor(v, 16));
            v = fmaxf(v, __shfl_xor(v, 32));
            cmx[j] = v;
        }
        if (rowg == 0) {
#pragma unroll
            for (int j = 0; j < 16; j++) colred[wv][colg + 8 * j] = cmx[j];
        }
        __syncthreads();
        if (t < TB) {
            const float v = fmaxf(fmaxf(colred[0][t], colred[1][t]),
                                  fmaxf(colred[2][t], colred[3][t]));
            Cxy[((size_t)b * T16 + I) * NN + (size_t)J * TB + t] =
                acos_raw(fminf(fmaxf(v, -CLIP), CLIP));
        }
    }
}

// ---------------------------------------------------------------------------
// Tile kernel (R10 structure — separate combine; R11 fusion regressed 2x).
// ach once per pair; two exp2 serve the two reduction directions with
// per-row / per-col shifts. Partials transposed [slot][globalrow].
// ---------------------------------------------------------------------------
struct TileArgs {
    const float* x; const float* y;
    const float* Wall; const float* Gall;
    const float* Rxx; const float* Ryy; const float* Rxy; const float* Cxy;
    float2* pAX; float2* pBY; float2* pAY; float2* pBX;
};

__global__ __launch_bounds__(256)
void tile_kernel(TileArgs A, float ieh, float pi_ieh)
{
    __shared__ float4 p1s[TB], p2s[TB];   // {px,py,pz,W}
    __shared__ float srs[TB], scs[TB];    // per-row / per-col shifts (scaled)
    __shared__ float colpart[4][TB];
    int kind, I, J; decode_tile(blockIdx.x, kind, I, J);
    const int b = blockIdx.y, t = threadIdx.x;
    const float* P1 = (kind == 1) ? A.y : A.x;
    const float* P2 = (kind == 0) ? A.x : A.y;
    const int o1 = (kind == 0) ? 0 : (kind == 1) ? 1 : 3;
    const int o2 = (kind == 0) ? 0 : (kind == 1) ? 1 : 2;
    float2* rowOut = (kind == 0) ? A.pAX : (kind == 1) ? A.pBY : A.pBX;
    float2* colOut = (kind == 0) ? A.pAX : (kind == 1) ? A.pBY : A.pAY;
    const bool diag = (kind < 2) && (I == J);
    const float* W1 = A.Wall + (size_t)o1 * SARR;
    const float* W2 = A.Wall + (size_t)o2 * SARR;
    const float* Rrow = (kind == 0) ? A.Rxx : (kind == 1) ? A.Ryy : A.Rxy;
    const float* Csrc = (kind == 0) ? A.Rxx : (kind == 1) ? A.Ryy : A.Cxy;

    // acos poly coefficients pre-scaled by ieh (log2 domain)
    const float K0 = 1.5707288f * ieh, K1 = -0.2121144f * ieh;
    const float K2 = 0.0742610f * ieh, K3 = -0.0187293f * ieh;

    if (t < TB) {
        size_t gi = (size_t)b * NN + (size_t)I * TB + t;
        p1s[t] = make_float4(P1[gi * 3], P1[gi * 3 + 1], P1[gi * 3 + 2], W1[gi]);
        srs[t] = Rrow[((size_t)b * T16 + J) * NN + (size_t)I * TB + t] * ieh;
    } else {
        int u = t - TB; size_t gi = (size_t)b * NN + (size_t)J * TB + u;
        p2s[u] = make_float4(P2[gi * 3], P2[gi * 3 + 1], P2[gi * 3 + 2], W2[gi]);
        scs[u] = Csrc[((size_t)b * T16 + I) * NN + (size_t)J * TB + u] * ieh;
    }
    const float G1 = A.Gall[o1 * 128 + b * T16 + I];
    const float G2 = A.Gall[o2 * 128 + b * T16 + J];
    __syncthreads();

    const int lane = t & 63, wv = t >> 6, colg = lane & 7, rowg = lane >> 3;
    const int r0 = wv * 32 + rowg * 4;
    float4 pr[4]; float srr[4];
#pragma unroll
    for (int rr = 0; rr < 4; rr++) { pr[rr] = p1s[r0 + rr]; srr[rr] = srs[r0 + rr]; }
    float racc[4] = {0.f, 0.f, 0.f, 0.f};
    float cacc[16];
#pragma unroll
    for (int j = 0; j < 16; j++) cacc[j] = 0.f;

#pragma unroll
    for (int j = 0; j < 16; j++) {
        const float4 q = p2s[colg + 8 * j];
        const float sc = scs[colg + 8 * j];
#pragma unroll
        for (int rr = 0; rr < 4; rr++) {
            const float4 p = pr[rr];
            const float d = fmaf(p.x, q.x, fmaf(p.y, q.y, p.z * q.z));
            const float u = fminf(fabsf(d), CLIP);   // sign from unclipped d
            float pl = fmaf(u, K3, K2); pl = fmaf(u, pl, K1); pl = fmaf(u, pl, K0);
            const float rt = __builtin_amdgcn_sqrtf(1.f - u) * pl;
            const float ach = (d >= 0.f) ? rt : (pi_ieh - rt);
            racc[rr] = fmaf(q.w, __builtin_amdgcn_exp2f(srr[rr] - ach), racc[rr]);
            cacc[j]  = fmaf(p.w, __builtin_amdgcn_exp2f(sc - ach), cacc[j]);
        }
    }

    // col sums: reduce across rowg (lane bits 3..5)
#pragma unroll
    for (int j = 0; j < 16; j++) {
        float v = cacc[j];
        v += __shfl_xor(v, 8); v += __shfl_xor(v, 16); v += __shfl_xor(v, 32);
        cacc[j] = v;
    }
    if (rowg == 0) {
#pragma unroll
        for (int j = 0; j < 16; j++) colpart[wv][colg + 8 * j] = cacc[j];
    }
    // row sums: reduce across colg (lane bits 0..2)
#pragma unroll
    for (int rr = 0; rr < 4; rr++) {
        float v = racc[rr];
        v += __shfl_xor(v, 1); v += __shfl_xor(v, 2); v += __shfl_xor(v, 4);
        racc[rr] = v;
    }
    if (colg == 0) {
        const size_t gr = (size_t)J * SARR + (size_t)b * NN + (size_t)I * TB + r0;
#pragma unroll
        for (int rr = 0; rr < 4; rr++)
            rowOut[gr + rr] = make_float2(G2 - srr[rr], racc[rr]);
    }
    __syncthreads();
    if (!diag && t < TB) {
        const float v = colpart[0][t] + colpart[1][t] + colpart[2][t] + colpart[3][t];
        const size_t gc = (size_t)I * SARR + (size_t)b * NN + (size_t)J * TB + t;
        colOut[gc] = make_float2(G1 - scs[t], v);
    }
}

// ---------------------------------------------------------------------------
// combine (steps 0..8): merge 16 (M,S) partials per row (coalesced);
// r = -eps*ln2*(M+log2 S); optional 0.5-averaging; emit next-step W, G.
// ---------------------------------------------------------------------------
__global__ __launch_bounds__(256)
void combine_kernel(const float2* __restrict__ pAX, const float2* __restrict__ pBY,
                    const float2* __restrict__ pAY, const float2* __restrict__ pBX,
                    float* __restrict__ ax, float* __restrict__ by,
                    float* __restrict__ ay, float* __restrict__ bx,
                    const float* __restrict__ gxw, const float* __restrict__ gyw,
                    float* __restrict__ Wall, float* __restrict__ Gall,
                    float eps_ln2, float nieL2E, int do_avg)
{
    const int tid = threadIdx.x;
    const int gid = blockIdx.x * 256 + tid;
    const int o = gid >> 14, i = gid & (SARR - 1);
    const float2* P = (o == 0) ? pAX : (o == 1) ? pBY : (o == 2) ? pAY : pBX;
    float* pot = (o == 0) ? ax : (o == 1) ? by : (o == 2) ? ay : bx;
    float r = finish16(P, i, -eps_ln2);
    if (do_avg) r = 0.5f * (r + pot[i]);
    pot[i] = r;
    const float g = ((o == 0 || o == 3) ? gxw[i] : gyw[i]) + r * nieL2E;
    __shared__ float red[256];
    red[tid] = g;
    __syncthreads();
    const int base = tid & 128, loc = tid & 127;
    for (int st = 64; st; st >>= 1) {
        if (loc < st) red[base + loc] = fmaxf(red[base + loc], red[base + loc + st]);
        __syncthreads();
    }
    const float G = red[base];
    Wall[gid] = __builtin_amdgcn_exp2f(g - G);
    if (loc == 0) Gall[gid >> 7] = G;
}

// ---------------------------------------------------------------------------
// final (step 9): finish all 4 sides per element and accumulate the loss.
// 64 blocks x 256 threads (1 elem/thread, coalesced partial reads);
// per-block reduce then one atomicAdd into out[b] (zeroed by maxes_kernel).
// ---------------------------------------------------------------------------
__global__ __launch_bounds__(256)
void final_kernel(const float2* __restrict__ pAX, const float2* __restrict__ pBY,
                  const float2* __restrict__ pAY, const float2* __restrict__ pBX,
                  const float* __restrict__ alpha, const float* __restrict__ beta,
                  float* __restrict__ out, float negepl2)
{
    const int t = threadIdx.x;
    const int gid = blockIdx.x * 256 + t;       // 64*256 = SARR threads
    const int b = gid >> 11;
    const float axv = finish16(pAX, gid, negepl2);
    const float bxv = finish16(pBX, gid, negepl2);
    const float ayv = finish16(pAY, gid, negepl2);
    const float byv = finish16(pBY, gid, negepl2);
    float acc = alpha[gid] * (bxv - axv) + beta[gid] * (ayv - byv);
    __shared__ float red[256];
    red[t] = acc;
    __syncthreads();
    for (int st = 128; st > 0; st >>= 1) {
        if (t < st) red[t] += red[t + st];
        __syncthreads();
    }
    if (t == 0) atomicAdd(&out[b], red[0]);
}

// ---------------------------------------------------------------------------
extern "C" void kernel_launch(void* const* d_in, const int* in_sizes, int n_in,
                              void* d_out, int out_size, void* d_ws, size_t ws_size,
                              hipStream_t stream)
{
    const float* alpha = (const float*)d_in[0];
    const float* x     = (const float*)d_in[1];
    const float* beta  = (const float*)d_in[2];
    const float* y     = (const float*)d_in[3];
    float* out = (float*)d_out;
    float* ws  = (float*)d_ws;

    const size_t S = SARR;
    float* gxw  = ws;
    float* gyw  = ws + S;
    float* ax   = ws + 2 * S;
    float* by   = ws + 3 * S;
    float* ay   = ws + 4 * S;
    float* bx   = ws + 5 * S;
    float* Wall = ws + 6 * S;              // 4*S
    float* Gall = ws + 10 * S;             // 512
    float* Rxx  = ws + 10 * S + 512;       // 16*S each (theta of max-dot)
    float* Ryy  = Rxx + 16 * S;
    float* Rxy  = Ryy + 16 * S;
    float* Cxy  = Rxy + 16 * S;
    float* pb   = Cxy + 16 * S;
    const size_t PSZ = (size_t)SARR * T16;
    float2* pAX = (float2*)pb;
    float2* pBY = pAX + PSZ;
    float2* pAY = pBY + PSZ;
    float2* pBX = pAY + PSZ;

    const float EPS[8] = {4.0f, 4.0f, 1.0f, 0.25f, 0.0625f, 0.015625f, 0.00390625f, 0.0025f};

    pack_kernel<<<(4 * SARR) / 256, 256, 0, stream>>>(alpha, beta, gxw, gyw, Wall, Gall);
    maxes_kernel<<<dim3(256, BB, 3), 256, 0, stream>>>(x, y, Rxx, Ryy, Rxy, Cxy, out);

    TileArgs TA;
    TA.x = x; TA.y = y; TA.Wall = Wall; TA.Gall = Gall;
    TA.Rxx = Rxx; TA.Ryy = Ryy; TA.Rxy = Rxy; TA.Cxy = Cxy;
    TA.pAX = pAX; TA.pBY = pBY; TA.pAY = pAY; TA.pBX = pBX;

    auto step = [&](float e, float next_e, int avg) {
        const float ieh = 0.5f * (1.f / e) * L2E;
        tile_kernel<<<dim3(NT, BB), 256, 0, stream>>>(TA, ieh, PI_F * ieh);
        combine_kernel<<<(4 * SARR) / 256, 256, 0, stream>>>(
            pAX, pBY, pAY, pBX, ax, by, ay, bx, gxw, gyw, Wall, Gall,
            e * LN2, (1.f / next_e) * L2E, avg);
    };

    step(EPS[0], EPS[0], 0);                                   // init
    for (int k = 0; k < 8; k++) step(EPS[k], (k < 7) ? EPS[k + 1] : EPS[7], 1);

    // final extrapolation: tile + fused finish/reduce (no combine dispatch)
    {
        const float ieh = 0.5f * (1.f / EPS[7]) * L2E;
        tile_kernel<<<dim3(NT, BB), 256, 0, stream>>>(TA, ieh, PI_F * ieh);
        final_kernel<<<SARR / 256, 256, 0, stream>>>(
            pAX, pBY, pAY, pBX, alpha, beta, out, -(EPS[7] * LN2));
    }
}

// Round 13
// 658.696 us; speedup vs baseline: 2.1323x; 1.0480x over previous
//
#include <hip/hip_runtime.h>
#include <math.h>

// Problem constants: B=8, N=M=2048, D=3.
#define BB 8
#define NN 2048
#define L2E 1.4426950408889634f
#define LN2 0.6931471805599453f
#define PI_F 3.14159265358979f
#define CLIP 0.999999f

constexpr int TB   = 128;
constexpr int T16  = NN / TB;              // 16
constexpr int NXX  = T16 * (T16 + 1) / 2;  // 136
constexpr int NT   = 2 * NXX + T16 * T16;  // 528 tiles per batch
constexpr int SARR = BB * NN;              // 16384

// tile index -> (kind, I, J). kind 0: xx (I<=J), 1: yy (I<=J), 2: xy (all)
__device__ __forceinline__ void decode_tile(int bx, int& kind, int& I, int& J) {
    if (bx < NXX) kind = 0;
    else if (bx < 2 * NXX) { kind = 1; bx -= NXX; }
    else { kind = 2; bx -= 2 * NXX; }
    if (kind < 2) {
        int idx = bx; I = 0;
        for (;;) { int len = T16 - I; if (idx < len) { J = I + idx; break; } idx -= len; I++; }
    } else { I = bx >> 4; J = bx & 15; }
}

// raw acos via A&S 4.4.45 (|err| <= 7e-5 rad), input pre-clipped
__device__ __forceinline__ float acos_raw(float d) {
    const float u = fabsf(d);
    float pl = fmaf(u, -0.0187293f, 0.0742610f);
    pl = fmaf(u, pl, -0.2121144f); pl = fmaf(u, pl, 1.5707288f);
    const float rt = __builtin_amdgcn_sqrtf(1.f - u) * pl;
    return (d >= 0.f) ? rt : (PI_F - rt);
}

// 16-slot (M,S) partial merge with zero-mass-slot guard -> negepl2*(M+log2 S)
__device__ __forceinline__ float finish16(const float2* __restrict__ P, size_t gi,
                                          float negepl2) {
    float M = -INFINITY, S = 0.f;
#pragma unroll
    for (int u = 0; u < T16; u++) {
        const float2 pr = P[(size_t)u * SARR + gi];
        if (pr.y > 0.f) {
            const float nm = fmaxf(M, pr.x);
            S = S * __builtin_amdgcn_exp2f(M - nm) + pr.y * __builtin_amdgcn_exp2f(pr.x - nm);
            M = nm;
        }
    }
    S = fmaxf(S, 1e-38f);
    return negepl2 * (M + __builtin_amdgcn_logf(S));
}

// ---------------------------------------------------------------------------
// pack: initial g = log_weights * log2(e); emit W = 2^{g-G}, per-128-block G.
// o in {0:a_x(x),1:b_y(y),2:a_y-side(y),3:b_x-side(x)}
// ---------------------------------------------------------------------------
__global__ __launch_bounds__(256)
void pack_kernel(const float* __restrict__ alpha, const float* __restrict__ beta,
                 float* __restrict__ gxw, float* __restrict__ gyw,
                 float* __restrict__ Wall, float* __restrict__ Gall)
{
    const int tid = threadIdx.x;
    const int gid = blockIdx.x * 256 + tid;
    const int o = gid >> 14, i = gid & (SARR - 1);
    const float* w = (o == 0 || o == 3) ? alpha : beta;
    const float v = w[i];
    const float g = ((v > 0.f) ? logf(fmaxf(v, 1e-30f)) : -1e5f) * L2E;
    if (o == 0) gxw[i] = g;
    if (o == 1) gyw[i] = g;
    __shared__ float red[256];
    red[tid] = g;
    __syncthreads();
    const int base = tid & 128, loc = tid & 127;
    for (int st = 64; st; st >>= 1) {
        if (loc < st) red[base + loc] = fmaxf(red[base + loc], red[base + loc + st]);
        __syncthreads();
    }
    const float G = red[base];
    Wall[gid] = __builtin_amdgcn_exp2f(g - G);
    if (loc == 0) Gall[gid >> 7] = G;
}

// ---------------------------------------------------------------------------
// One-time geometry pass over FULL tile grids (kind = blockIdx.z).
// Stores THETA of the per-row / per-col max-dot (eps-independent).
// Also zeroes out[] (final kernel accumulates with atomics).
// ---------------------------------------------------------------------------
__global__ __launch_bounds__(256)
void maxes_kernel(const float* __restrict__ x, const float* __restrict__ y,
                  float* __restrict__ Rxx, float* __restrict__ Ryy,
                  float* __restrict__ Rxy, float* __restrict__ Cxy,
                  float* __restrict__ out)
{
    __shared__ float4 p1s[TB], p2s[TB];
    __shared__ float colred[4][TB];
    const int I = blockIdx.x >> 4, J = blockIdx.x & 15;
    const int b = blockIdx.y, kind = blockIdx.z, t = threadIdx.x;
    if (blockIdx.x == 0 && b == 0 && kind == 0 && t < BB) out[t] = 0.f;
    const float* P1 = (kind == 1) ? y : x;
    const float* P2 = (kind == 0) ? x : y;
    if (t < TB) {
        size_t gi = (size_t)b * NN + (size_t)I * TB + t;
        p1s[t] = make_float4(P1[gi * 3], P1[gi * 3 + 1], P1[gi * 3 + 2], 0.f);
    } else {
        int u = t - TB; size_t gi = (size_t)b * NN + (size_t)J * TB + u;
        p2s[u] = make_float4(P2[gi * 3], P2[gi * 3 + 1], P2[gi * 3 + 2], 0.f);
    }
    __syncthreads();
    const int lane = t & 63, wv = t >> 6, colg = lane & 7, rowg = lane >> 3;
    const int r0 = wv * 32 + rowg * 4;
    float4 pr[4];
#pragma unroll
    for (int rr = 0; rr < 4; rr++) pr[rr] = p1s[r0 + rr];
    float rmx[4] = {-2.f, -2.f, -2.f, -2.f};
    float cmx[16];
#pragma unroll
    for (int j = 0; j < 16; j++) cmx[j] = -2.f;
#pragma unroll
    for (int j = 0; j < 16; j++) {
        const float4 q = p2s[colg + 8 * j];
#pragma unroll
        for (int rr = 0; rr < 4; rr++) {
            float d = fmaf(pr[rr].x, q.x, fmaf(pr[rr].y, q.y, pr[rr].z * q.z));
            rmx[rr] = fmaxf(rmx[rr], d);
            cmx[j] = fmaxf(cmx[j], d);
        }
    }
#pragma unroll
    for (int rr = 0; rr < 4; rr++) {
        float v = rmx[rr];
        v = fmaxf(v, __shfl_xor(v, 1)); v = fmaxf(v, __shfl_xor(v, 2));
        v = fmaxf(v, __shfl_xor(v, 4));
        rmx[rr] = v;
    }
    if (colg == 0) {
        float* R = (kind == 0) ? Rxx : (kind == 1) ? Ryy : Rxy;
        const size_t base = ((size_t)b * T16 + J) * NN + (size_t)I * TB + r0;
#pragma unroll
        for (int rr = 0; rr < 4; rr++)
            R[base + rr] = acos_raw(fminf(fmaxf(rmx[rr], -CLIP), CLIP));
    }
    if (kind == 2) {
#pragma unroll
        for (int j = 0; j < 16; j++) {
            float v = cmx[j];
            v = fmaxf(v, __shfl_xor(v, 8)); v = fmaxf(v, __shfl_xor(v, 16));
            v = fmaxf(v, __shfl_xor(v, 32));
            cmx[j] = v;
        }
        if (rowg == 0) {
#pragma unroll
            for (int j = 0; j < 16; j++) colred[wv][colg + 8 * j] = cmx[j];
        }
        __syncthreads();
        if (t < TB) {
            const float v = fmaxf(fmaxf(colred[0][t], colred[1][t]),
                                  fmaxf(colred[2][t], colred[3][t]));
            Cxy[((size_t)b * T16 + I) * NN + (size_t)J * TB + t] =
                acos_raw(fminf(fmaxf(v, -CLIP), CLIP));
        }
    }
}

// ---------------------------------------------------------------------------
// Tile kernel — EXACT R10 inner loop (both-sided clamp on d; abs folds into
// a free VOP3 modifier, keeping only d live: 84 VGPR / ~26% occupancy.
// R12's u=min(abs(d),CLIP) variant kept d AND u live -> 96 VGPR, 18% occ,
// 51.7 -> 65.4 µs regression).
// ---------------------------------------------------------------------------
struct TileArgs {
    const float* x; const float* y;
    const float* Wall; const float* Gall;
    const float* Rxx; const float* Ryy; const float* Rxy; const float* Cxy;
    float2* pAX; float2* pBY; float2* pAY; float2* pBX;
};

__global__ __launch_bounds__(256)
void tile_kernel(TileArgs A, float ieh, float pi_ieh)
{
    __shared__ float4 p1s[TB], p2s[TB];   // {px,py,pz,W}
    __shared__ float srs[TB], scs[TB];    // per-row / per-col shifts (scaled)
    __shared__ float colpart[4][TB];
    int kind, I, J; decode_tile(blockIdx.x, kind, I, J);
    const int b = blockIdx.y, t = threadIdx.x;
    const float* P1 = (kind == 1) ? A.y : A.x;
    const float* P2 = (kind == 0) ? A.x : A.y;
    const int o1 = (kind == 0) ? 0 : (kind == 1) ? 1 : 3;
    const int o2 = (kind == 0) ? 0 : (kind == 1) ? 1 : 2;
    float2* rowOut = (kind == 0) ? A.pAX : (kind == 1) ? A.pBY : A.pBX;
    float2* colOut = (kind == 0) ? A.pAX : (kind == 1) ? A.pBY : A.pAY;
    const bool diag = (kind < 2) && (I == J);
    const float* W1 = A.Wall + (size_t)o1 * SARR;
    const float* W2 = A.Wall + (size_t)o2 * SARR;
    const float* Rrow = (kind == 0) ? A.Rxx : (kind == 1) ? A.Ryy : A.Rxy;
    const float* Csrc = (kind == 0) ? A.Rxx : (kind == 1) ? A.Ryy : A.Cxy;

    // acos poly coefficients pre-scaled by ieh (log2 domain)
    const float K0 = 1.5707288f * ieh, K1 = -0.2121144f * ieh;
    const float K2 = 0.0742610f * ieh, K3 = -0.0187293f * ieh;

    if (t < TB) {
        size_t gi = (size_t)b * NN + (size_t)I * TB + t;
        p1s[t] = make_float4(P1[gi * 3], P1[gi * 3 + 1], P1[gi * 3 + 2], W1[gi]);
        srs[t] = Rrow[((size_t)b * T16 + J) * NN + (size_t)I * TB + t] * ieh;
    } else {
        int u = t - TB; size_t gi = (size_t)b * NN + (size_t)J * TB + u;
        p2s[u] = make_float4(P2[gi * 3], P2[gi * 3 + 1], P2[gi * 3 + 2], W2[gi]);
        scs[u] = Csrc[((size_t)b * T16 + I) * NN + (size_t)J * TB + u] * ieh;
    }
    const float G1 = A.Gall[o1 * 128 + b * T16 + I];
    const float G2 = A.Gall[o2 * 128 + b * T16 + J];
    __syncthreads();

    const int lane = t & 63, wv = t >> 6, colg = lane & 7, rowg = lane >> 3;
    const int r0 = wv * 32 + rowg * 4;
    float4 pr[4]; float srr[4];
#pragma unroll
    for (int rr = 0; rr < 4; rr++) { pr[rr] = p1s[r0 + rr]; srr[rr] = srs[r0 + rr]; }
    float racc[4] = {0.f, 0.f, 0.f, 0.f};
    float cacc[16];
#pragma unroll
    for (int j = 0; j < 16; j++) cacc[j] = 0.f;

#pragma unroll
    for (int j = 0; j < 16; j++) {
        const float4 q = p2s[colg + 8 * j];
        const float sc = scs[colg + 8 * j];
#pragma unroll
        for (int rr = 0; rr < 4; rr++) {
            const float4 p = pr[rr];
            float d = fmaf(p.x, q.x, fmaf(p.y, q.y, p.z * q.z));
            d = fminf(fmaxf(d, -CLIP), CLIP);
            const float u = fabsf(d);
            float pl = fmaf(u, K3, K2); pl = fmaf(u, pl, K1); pl = fmaf(u, pl, K0);
            const float rt = __builtin_amdgcn_sqrtf(1.f - u) * pl;
            const float ach = (d >= 0.f) ? rt : (pi_ieh - rt);
            racc[rr] = fmaf(q.w, __builtin_amdgcn_exp2f(srr[rr] - ach), racc[rr]);
            cacc[j]  = fmaf(p.w, __builtin_amdgcn_exp2f(sc - ach), cacc[j]);
        }
    }

    // col sums: reduce across rowg (lane bits 3..5)
#pragma unroll
    for (int j = 0; j < 16; j++) {
        float v = cacc[j];
        v += __shfl_xor(v, 8); v += __shfl_xor(v, 16); v += __shfl_xor(v, 32);
        cacc[j] = v;
    }
    if (rowg == 0) {
#pragma unroll
        for (int j = 0; j < 16; j++) colpart[wv][colg + 8 * j] = cacc[j];
    }
    // row sums: reduce across colg (lane bits 0..2)
#pragma unroll
    for (int rr = 0; rr < 4; rr++) {
        float v = racc[rr];
        v += __shfl_xor(v, 1); v += __shfl_xor(v, 2); v += __shfl_xor(v, 4);
        racc[rr] = v;
    }
    if (colg == 0) {
        const size_t gr = (size_t)J * SARR + (size_t)b * NN + (size_t)I * TB + r0;
#pragma unroll
        for (int rr = 0; rr < 4; rr++)
            rowOut[gr + rr] = make_float2(G2 - srr[rr], racc[rr]);
    }
    __syncthreads();
    if (!diag && t < TB) {
        const float v = colpart[0][t] + colpart[1][t] + colpart[2][t] + colpart[3][t];
        const size_t gc = (size_t)I * SARR + (size_t)b * NN + (size_t)J * TB + t;
        colOut[gc] = make_float2(G1 - scs[t], v);
    }
}

// ---------------------------------------------------------------------------
// combine (steps 0..8): merge 16 (M,S) partials per row (coalesced);
// r = -eps*ln2*(M+log2 S); optional 0.5-averaging; emit next-step W, G.
// ---------------------------------------------------------------------------
__global__ __launch_bounds__(256)
void combine_kernel(const float2* __restrict__ pAX, const float2* __restrict__ pBY,
                    const float2* __restrict__ pAY, const float2* __restrict__ pBX,
                    float* __restrict__ ax, float* __restrict__ by,
                    float* __restrict__ ay, float* __restrict__ bx,
                    const float* __restrict__ gxw, const float* __restrict__ gyw,
                    float* __restrict__ Wall, float* __restrict__ Gall,
                    float eps_ln2, float nieL2E, int do_avg)
{
    const int tid = threadIdx.x;
    const int gid = blockIdx.x * 256 + tid;
    const int o = gid >> 14, i = gid & (SARR - 1);
    const float2* P = (o == 0) ? pAX : (o == 1) ? pBY : (o == 2) ? pAY : pBX;
    float* pot = (o == 0) ? ax : (o == 1) ? by : (o == 2) ? ay : bx;
    float r = finish16(P, i, -eps_ln2);
    if (do_avg) r = 0.5f * (r + pot[i]);
    pot[i] = r;
    const float g = ((o == 0 || o == 3) ? gxw[i] : gyw[i]) + r * nieL2E;
    __shared__ float red[256];
    red[tid] = g;
    __syncthreads();
    const int base = tid & 128, loc = tid & 127;
    for (int st = 64; st; st >>= 1) {
        if (loc < st) red[base + loc] = fmaxf(red[base + loc], red[base + loc + st]);
        __syncthreads();
    }
    const float G = red[base];
    Wall[gid] = __builtin_amdgcn_exp2f(g - G);
    if (loc == 0) Gall[gid >> 7] = G;
}

// ---------------------------------------------------------------------------
// final (step 9): finish all 4 sides per element and accumulate the loss.
// 64 blocks x 256 threads (1 elem/thread, coalesced partial reads);
// per-block reduce then one atomicAdd into out[b] (zeroed by maxes_kernel).
// ---------------------------------------------------------------------------
__global__ __launch_bounds__(256)
void final_kernel(const float2* __restrict__ pAX, const float2* __restrict__ pBY,
                  const float2* __restrict__ pAY, const float2* __restrict__ pBX,
                  const float* __restrict__ alpha, const float* __restrict__ beta,
                  float* __restrict__ out, float negepl2)
{
    const int t = threadIdx.x;
    const int gid = blockIdx.x * 256 + t;       // 64*256 = SARR threads
    const int b = gid >> 11;
    const float axv = finish16(pAX, gid, negepl2);
    const float bxv = finish16(pBX, gid, negepl2);
    const float ayv = finish16(pAY, gid, negepl2);
    const float byv = finish16(pBY, gid, negepl2);
    float acc = alpha[gid] * (bxv - axv) + beta[gid] * (ayv - byv);
    __shared__ float red[256];
    red[t] = acc;
    __syncthreads();
    for (int st = 128; st > 0; st >>= 1) {
        if (t < st) red[t] += red[t + st];
        __syncthreads();
    }
    if (t == 0) atomicAdd(&out[b], red[0]);
}

// ---------------------------------------------------------------------------
extern "C" void kernel_launch(void* const* d_in, const int* in_sizes, int n_in,
                              void* d_out, int out_size, void* d_ws, size_t ws_size,
                              hipStream_t stream)
{
    const float* alpha = (const float*)d_in[0];
    const float* x     = (const float*)d_in[1];
    const float* beta  = (const float*)d_in[2];
    const float* y     = (const float*)d_in[3];
    float* out = (float*)d_out;
    float* ws  = (float*)d_ws;

    const size_t S = SARR;
    float* gxw  = ws;
    float* gyw  = ws + S;
    float* ax   = ws + 2 * S;
    float* by   = ws + 3 * S;
    float* ay   = ws + 4 * S;
    float* bx   = ws + 5 * S;
    float* Wall = ws + 6 * S;              // 4*S
    float* Gall = ws + 10 * S;             // 512
    float* Rxx  = ws + 10 * S + 512;       // 16*S each (theta of max-dot)
    float* Ryy  = Rxx + 16 * S;
    float* Rxy  = Ryy + 16 * S;
    float* Cxy  = Rxy + 16 * S;
    float* pb   = Cxy + 16 * S;
    const size_t PSZ = (size_t)SARR * T16;
    float2* pAX = (float2*)pb;
    float2* pBY = pAX + PSZ;
    float2* pAY = pBY + PSZ;
    float2* pBX = pAY + PSZ;

    const float EPS[8] = {4.0f, 4.0f, 1.0f, 0.25f, 0.0625f, 0.015625f, 0.00390625f, 0.0025f};

    pack_kernel<<<(4 * SARR) / 256, 256, 0, stream>>>(alpha, beta, gxw, gyw, Wall, Gall);
    maxes_kernel<<<dim3(256, BB, 3), 256, 0, stream>>>(x, y, Rxx, Ryy, Rxy, Cxy, out);

    TileArgs TA;
    TA.x = x; TA.y = y; TA.Wall = Wall; TA.Gall = Gall;
    TA.Rxx = Rxx; TA.Ryy = Ryy; TA.Rxy = Rxy; TA.Cxy = Cxy;
    TA.pAX = pAX; TA.pBY = pBY; TA.pAY = pAY; TA.pBX = pBX;

    auto step = [&](float e, float next_e, int avg) {
        const float ieh = 0.5f * (1.f / e) * L2E;
        tile_kernel<<<dim3(NT, BB), 256, 0, stream>>>(TA, ieh, PI_F * ieh);
        combine_kernel<<<(4 * SARR) / 256, 256, 0, stream>>>(
            pAX, pBY, pAY, pBX, ax, by, ay, bx, gxw, gyw, Wall, Gall,
            e * LN2, (1.f / next_e) * L2E, avg);
    };

    step(EPS[0], EPS[0], 0);                                   // init
    for (int k = 0; k < 8; k++) step(EPS[k], (k < 7) ? EPS[k + 1] : EPS[7], 1);

    // final extrapolation: tile + fused finish/reduce (no combine dispatch)
    {
        const float ieh = 0.5f * (1.f / EPS[7]) * L2E;
        tile_kernel<<<dim3(NT, BB), 256, 0, stream>>>(TA, ieh, PI_F * ieh);
        final_kernel<<<SARR / 256, 256, 0, stream>>>(
            pAX, pBY, pAY, pBX, alpha, beta, out, -(EPS[7] * LN2));
    }
}